// Round 8
// baseline (334.168 us; speedup 1.0000x reference)
//
#include <hip/hip_runtime.h>
#include <hip/hip_bf16.h>
#include <math.h>
#include <stdint.h>

// Disable FP contraction: tie-breaking (quality = 1e8 - area, ulp=8 at 1e8)
// and decode must bit-match the mul-then-round numpy reference.
#pragma clang fp contract(off)

#define NB   16
#define NC   20
#define NM   64
#define NT   21504
#define OFF1 16384
#define OFF2 20480
#define TOPK 1000
#define DELTA_OFF 80000L
#define CTR_OFF   1456256L

// workspace layout (float units)
#define WS_SCORES   0L
#define WS_BOXESW   344064L
#define WS_CIDW     1720320L

// ---------- dtype helpers (bf: 0 = float32, 1 = bf16) ----------
__device__ __forceinline__ int detect_bf(const void* locs0) {
  unsigned w = *(const unsigned*)locs0;      // f32 4.0 = 0x40800000 (low16==0)
  return ((w & 0xFFFFu) == 0u) ? 0 : 1;
}
__device__ __forceinline__ float ldin(const void* p, long i, int bf) {
  if (bf) return __uint_as_float(((unsigned)((const unsigned short*)p)[i]) << 16);
  return ((const float*)p)[i];
}
__device__ __forceinline__ unsigned short f2bf(float v) {
  unsigned w = __float_as_uint(v);
  return (unsigned short)((w + 0x7FFFu + ((w >> 16) & 1u)) >> 16);  // RNE
}
__device__ __forceinline__ void stout(void* p, long i, float v, int bf) {
  if (bf) ((unsigned short*)p)[i] = f2bf(v);
  else    ((float*)p)[i] = v;
}

// ---------- K1: fused targets + scores/decode (proven) ----------
__global__ __launch_bounds__(256)
void k_main(const void* locs0, const void* locs1, const void* locs2,
            const void* gt,
            const void* cls0, const void* cls1, const void* cls2,
            const void* reg0, const void* reg1, const void* reg2,
            const void* ctr0, const void* ctr1, const void* ctr2,
            void* out, float* scores, float* boxesw, float* cidw) {
  __shared__ float sgt[NM * 5];
  const int bf  = detect_bf(locs0);
  const int b   = blockIdx.y;
  const int blk = blockIdx.x;
  const int tid = threadIdx.x;
  const int n   = blk * 256 + tid;

  const void *L, *CL, *RG, *CT; int NL, base; float stride, lower, upper;
  if (blk < 64)      { L=locs0; CL=cls0; RG=reg0; CT=ctr0; NL=16384; base=0;    stride=8.f;  lower=0.f;   upper=64.f; }
  else if (blk < 80) { L=locs1; CL=cls1; RG=reg1; CT=ctr1; NL=4096;  base=OFF1; stride=16.f; lower=64.f;  upper=128.f; }
  else               { L=locs2; CL=cls2; RG=reg2; CT=ctr2; NL=1024;  base=OFF2; stride=32.f; lower=128.f; upper=INFINITY; }
  const int nl = n - base;

  for (int i = tid; i < NM * 5; i += 256) sgt[i] = ldin(gt, (long)b * NM * 5 + i, bf);
  __syncthreads();

  float cx = ldin(L, (long)nl * 2 + 0, bf);
  float cy = ldin(L, (long)nl * 2 + 1, bf);

  // ---- GT matching / targets ----
  float best = -1.0f; int bi = 0;              // argmax-first (strict >)
  for (int m = 0; m < NM; ++m) {
    float g0 = sgt[m*5+0], g1 = sgt[m*5+1], g2 = sgt[m*5+2], g3 = sgt[m*5+3];
    float l = cx - g0, t = cy - g1, r = g2 - cx, d = g3 - cy;
    float mn = fminf(fminf(l, t), fminf(r, d));
    float mx = fmaxf(fmaxf(l, t), fmaxf(r, d));
    bool  ok = (mn > 0.f) && (mx > lower) && (mx < upper);
    float area = (g2 - g0) * (g3 - g1);
    float q = ok ? (100000000.0f - area) : 0.f;
    if (q > best) { best = q; bi = m; }
  }
  float d0, d1, d2, d3, ctrv;
  if (best < 1e-5f) {
    d0 = d1 = d2 = d3 = -1.f; ctrv = -1.f;
  } else {
    float m0 = sgt[bi*5+0], m1 = sgt[bi*5+1], m2 = sgt[bi*5+2], m3 = sgt[bi*5+3];
    d0 = (cx - m0) / stride; d1 = (cy - m1) / stride;
    d2 = (m2 - cx) / stride; d3 = (m3 - cy) / stride;
    float mnlr = fminf(d0, d2), mntb = fminf(d1, d3);
    float mxlr = fmaxf(d0, d2), mxtb = fmaxf(d1, d3);
    ctrv = sqrtf((mnlr * mntb) / (mxlr * mxtb));
  }
  long dbase = DELTA_OFF + ((long)b * NT + n) * 4;
  if (!bf) {
    *(float4*)((float*)out + dbase) = make_float4(d0, d1, d2, d3);
  } else {
    ushort4 v; v.x = f2bf(d0); v.y = f2bf(d1); v.z = f2bf(d2); v.w = f2bf(d3);
    *(ushort4*)((unsigned short*)out + dbase) = v;
  }
  stout(out, CTR_OFF + (long)b * NT + n, ctrv, bf);

  // ---- scores: argmax over sigmoid == argmax over logits (monotone) ----
  float ct  = ldin(CT, (long)b * NL + nl, bf);
  float sct = 1.0f / (1.0f + expf(-ct));

  float cl[NC];
  long cb = ((long)b * NL + nl) * NC;
  if (!bf) {
    const float4* p = (const float4*)((const float*)CL + cb);   // cb*4 % 16 == 0
#pragma unroll
    for (int i = 0; i < 5; ++i) {
      float4 q = p[i];
      cl[4*i+0] = q.x; cl[4*i+1] = q.y; cl[4*i+2] = q.z; cl[4*i+3] = q.w;
    }
  } else {
    const uint2* p = (const uint2*)((const unsigned short*)CL + cb);  // cb*2 % 8 == 0
#pragma unroll
    for (int i = 0; i < 5; ++i) {
      uint2 q = p[i];
      cl[4*i+0] = __uint_as_float((q.x & 0xFFFFu) << 16);
      cl[4*i+1] = __uint_as_float(q.x & 0xFFFF0000u);
      cl[4*i+2] = __uint_as_float((q.y & 0xFFFFu) << 16);
      cl[4*i+3] = __uint_as_float(q.y & 0xFFFF0000u);
    }
  }
  float vmax = cl[0], v2 = -INFINITY; int ci = 0;
#pragma unroll
  for (int c = 1; c < NC; ++c) {
    if (cl[c] > vmax) { v2 = vmax; vmax = cl[c]; ci = c; }
    else if (cl[c] > v2) v2 = cl[c];
  }
  float smax;
  if (vmax - v2 < 1e-3f) {
    // sigmoid-plateau risk: replicate the reference loop exactly (strict >, first idx)
    smax = -1.0f; ci = 0;
    for (int c = 0; c < NC; ++c) {
      float sv = 1.0f / (1.0f + expf(-cl[c]));
      float s  = sqrtf(sv * sct);
      if (s > smax) { smax = s; ci = c; }
    }
  } else {
    float sv = 1.0f / (1.0f + expf(-vmax));
    smax = sqrtf(sv * sct);      // == ref's max: RN is monotone under *sct and sqrt
  }

  // ---- decode ----
  float r0, r1, r2, r3;
  long rbase = ((long)b * NL + nl) * 4;
  if (!bf) {
    float4 rv = *(const float4*)((const float*)RG + rbase);
    r0 = rv.x; r1 = rv.y; r2 = rv.z; r3 = rv.w;
  } else {
    uint2 rw = *(const uint2*)((const unsigned short*)RG + rbase);
    r0 = __uint_as_float((rw.x & 0xFFFFu) << 16); r1 = __uint_as_float(rw.x & 0xFFFF0000u);
    r2 = __uint_as_float((rw.y & 0xFFFFu) << 16); r3 = __uint_as_float(rw.y & 0xFFFF0000u);
  }
  r0 = fmaxf(r0, 0.f); r1 = fmaxf(r1, 0.f); r2 = fmaxf(r2, 0.f); r3 = fmaxf(r3, 0.f);
  long o = (long)b * NT + n;
  scores[o] = smax;
  *(float4*)(boxesw + o * 4) =
      make_float4(cx - r0 * stride, cy - r1 * stride, cx + r2 * stride, cy + r3 * stride);
  cidw[o] = (float)ci;
}

// ---------- wave64 inclusive scan ----------
__device__ __forceinline__ unsigned wscan(unsigned v, int lane) {
  for (int off = 1; off < 64; off <<= 1) {
    unsigned u = __shfl_up(v, off);
    if (lane >= off) v += u;
  }
  return v;
}

// ---------- K2: top-1000 select + sort + single-wave barrier-free NMS ----------
__global__ __launch_bounds__(1024)
void k_post(const float* scores, const float* boxesw, const float* cidw,
            void* out, const void* locs0) {
  const int bf   = detect_bf(locs0);
  const int b    = blockIdx.x;
  const int tid  = threadIdx.x;
  const int wid  = tid >> 6;
  const int lane = tid & 63;
  const float* sb = scores + (long)b * NT;

  __shared__ unsigned hist[8192];                       // 32 KB; aliased below
  unsigned long long* selKeys = (unsigned long long*)hist;  // [1024], alias (sort)
  float*              sb5     = (float*)hist;               // [1024*5], alias (NMS)
  __shared__ unsigned wsum[16];
  __shared__ unsigned sTop, sBefore, sBinCnt, sSub, selCnt;
  __shared__ float redf[16];
  __shared__ float sMaxC;
  __shared__ unsigned long long smask[16];
  __shared__ unsigned long long keepW[16];

  // ============ Phase A: exact top-1000 (histogram select + hybrid bitonic) ====
  unsigned inv[21];
#pragma unroll
  for (int k = 0; k < 21; ++k)
    inv[k] = ~__float_as_uint(sb[tid + k * 1024]);

  // level 1: histogram of inv>>17 (top 2 bits always 11 -> 8192 bins)
  for (int i = tid; i < 8192; i += 1024) hist[i] = 0u;
  __syncthreads();
#pragma unroll
  for (int k = 0; k < 21; ++k)
    atomicAdd(&hist[(inv[k] >> 17) - 0x6000u], 1u);
  __syncthreads();
  {
    unsigned hloc[8], s0 = 0;
#pragma unroll
    for (int j = 0; j < 8; ++j) { hloc[j] = hist[8 * tid + j]; s0 += hloc[j]; }
    unsigned sc = wscan(s0, lane);
    if (lane == 63) wsum[wid] = sc;
    __syncthreads();
    unsigned basev = 0;
    for (int w = 0; w < wid; ++w) basev += wsum[w];
    unsigned cumBefore = basev + sc - s0;
    if (cumBefore < TOPK && cumBefore + s0 >= TOPK) {
      unsigned c = cumBefore;
#pragma unroll
      for (int j = 0; j < 8; ++j) {
        if (c + hloc[j] >= TOPK) {
          sTop = (8 * tid + j) + 0x6000u; sBefore = c; sBinCnt = hloc[j]; break;
        }
        c += hloc[j];
      }
    }
  }
  __syncthreads();
  const unsigned topBits = sTop;
  const unsigned r = TOPK - sBefore;

  unsigned long long cutEnd;
  if (sBefore + sBinCnt <= 1024u) {
    // whole boundary bin fits the 1024 gather budget: skip level 2 (uniform branch)
    cutEnd = ((unsigned long long)(topBits + 1u)) << 17;
  } else {
    // level 2: histogram of bits 16..4 within boundary bin
    for (int i = tid; i < 8192; i += 1024) hist[i] = 0u;
    __syncthreads();
#pragma unroll
    for (int k = 0; k < 21; ++k)
      if ((inv[k] >> 17) == topBits) atomicAdd(&hist[(inv[k] >> 4) & 0x1FFFu], 1u);
    __syncthreads();
    {
      unsigned hloc[8], s0 = 0;
#pragma unroll
      for (int j = 0; j < 8; ++j) { hloc[j] = hist[8 * tid + j]; s0 += hloc[j]; }
      unsigned sc = wscan(s0, lane);
      if (lane == 63) wsum[wid] = sc;
      __syncthreads();
      unsigned basev = 0;
      for (int w = 0; w < wid; ++w) basev += wsum[w];
      unsigned cumBefore = basev + sc - s0;
      if (cumBefore < r && cumBefore + s0 >= r) {
        unsigned c = cumBefore;
#pragma unroll
        for (int j = 0; j < 8; ++j) {
          if (c + hloc[j] >= r) { sSub = 8 * tid + j; break; }
          c += hloc[j];
        }
      }
    }
    __syncthreads();
    cutEnd = ((unsigned long long)topBits << 17) |
             ((unsigned long long)(sSub + 1u) << 4);
  }
  if (tid == 0) selCnt = 0u;
  __syncthreads();   // hist reads done; selKeys alias safe

#pragma unroll
  for (int k = 0; k < 21; ++k)
    if ((unsigned long long)inv[k] < cutEnd) {
      unsigned p = atomicAdd(&selCnt, 1u);
      if (p < 1024u) selKeys[p] = ((unsigned long long)inv[k] << 32) | (unsigned)(tid + k * 1024);
    }
  __syncthreads();
  unsigned total = selCnt < 1024u ? selCnt : 1024u;
  unsigned long long key =
      ((unsigned)tid < total) ? selKeys[tid] : 0xFFFFFFFFFFFFFFFFull;
  __syncthreads();

  // hybrid bitonic sort ascending: (inv asc, idx asc) == (score desc, idx asc)
  for (unsigned k = 2; k <= 1024; k <<= 1) {
    for (unsigned j = k >> 1; j > 0; j >>= 1) {
      unsigned long long other;
      if (j >= 64) {
        selKeys[tid] = key; __syncthreads();
        other = selKeys[tid ^ j]; __syncthreads();
      } else {
        other = __shfl(key, (int)(lane ^ j));
      }
      bool up = ((tid & k) == 0);
      bool takeMin = (((tid & j) == 0) == up);
      key = takeMin ? (key < other ? key : other) : (key > other ? key : other);
    }
  }

  // ---- gather box/score/cls (registers) ----
  float sc = __uint_as_float(~(unsigned)(key >> 32));
  float4 bv = make_float4(0.f, 0.f, 0.f, 0.f);
  float cid = 0.f;
  if (tid < TOPK) {
    long o = (long)b * NT + (unsigned)key;
    bv = *(const float4*)(boxesw + o * 4);
    cid = cidw[o];
  } else sc = 0.f;

  // ---- max_coord = max(where(valid, bx, 0)) ----
  float loc = (tid < TOPK)
      ? ((sc > 0.3f) ? fmaxf(fmaxf(bv.x, bv.y), fmaxf(bv.z, bv.w)) : 0.0f)
      : -INFINITY;
  for (int o = 32; o > 0; o >>= 1) loc = fmaxf(loc, __shfl_down(loc, o));
  if (lane == 0) redf[wid] = loc;
  __syncthreads();
  if (tid == 0) {
    float m = redf[0];
    for (int w = 1; w < 16; ++w) m = fmaxf(m, redf[w]);
    sMaxC = m;
  }
  __syncthreads();

  // ---- shifted box + area -> LDS stride-5 (conflict-free); act ballot words ----
  float offm = sMaxC + 1.0f;
  float o4 = cid * offm;
  float s0 = bv.x + o4, s1 = bv.y + o4, s2 = bv.z + o4, s3 = bv.w + o4;
  float myArea = (s2 - s0) * (s3 - s1);
  sb5[tid*5+0] = s0; sb5[tid*5+1] = s1; sb5[tid*5+2] = s2; sb5[tid*5+3] = s3;
  sb5[tid*5+4] = myArea;
  bool valid = (tid < TOPK) && (sc > 0.3f);
  unsigned long long vb = __ballot(valid);
  if (lane == 0) smask[wid] = vb;
  __syncthreads();

  // ============ Phase B: single-wave greedy NMS (ZERO barriers in pick chain) ====
  // lane L owns rows r = j*64 + L (j = 0..15) as a 16-bit register mask.
  if (wid == 0) {
    unsigned mask = 0u, keep16 = 0u;
#pragma unroll
    for (int j = 0; j < 16; ++j)
      mask |= (unsigned)((smask[j] >> lane) & 1ull) << j;   // broadcast reads

    int cand = mask ? ((__ffs(mask) - 1) * 64 + lane) : 0x7FFFFFFF;
    for (int o = 32; o > 0; o >>= 1) cand = min(cand, __shfl_down(cand, o));
    int pick = __shfl(cand, 0);

    int kept = 0;
    while (pick < 0x7FFFFFFF && kept < 100) {
      ++kept;
      if (lane == (pick & 63)) keep16 |= 1u << (pick >> 6);
      float p0 = sb5[pick*5+0], p1 = sb5[pick*5+1];        // same-addr: broadcast
      float p2 = sb5[pick*5+2], p3 = sb5[pick*5+3], pa = sb5[pick*5+4];
      unsigned m = mask;
      while (m) {                                          // only still-active rows
        int j = __ffs(m) - 1; m &= m - 1;
        int rr = j * 64 + lane;
        float q0 = sb5[rr*5+0], q1 = sb5[rr*5+1];
        float q2 = sb5[rr*5+2], q3 = sb5[rr*5+3], qa = sb5[rr*5+4];
        float xx1 = fmaxf(p0, q0), yy1 = fmaxf(p1, q1);
        float xx2 = fminf(p2, q2), yy2 = fminf(p3, q3);
        float inter = fmaxf(xx2 - xx1, 0.f) * fmaxf(yy2 - yy1, 0.f);
        float iou = inter / (pa + qa - inter);             // exact div: ref rounding
        if (!(iou <= 0.5f)) mask &= ~(1u << j);            // NaN suppresses (self too)
      }
      cand = mask ? ((__ffs(mask) - 1) * 64 + lane) : 0x7FFFFFFF;
      for (int o = 32; o > 0; o >>= 1) cand = min(cand, __shfl_down(cand, o));
      pick = __shfl(cand, 0);
    }
#pragma unroll
    for (int j = 0; j < 16; ++j) {
      unsigned long long kb = __ballot((keep16 >> j) & 1u);
      if (lane == 0) keepW[j] = kb;                        // row r=j*64+L -> word j bit L
    }
  }
  __syncthreads();

  // ---- det write from registers ----
  bool mykeep = (keepW[tid >> 6] >> (tid & 63)) & 1ull;
  if (tid < TOPK) {
    long o = ((long)b * TOPK + tid) * 5;
    stout(out, o + 0, mykeep ? bv.x : 0.f, bf);
    stout(out, o + 1, mykeep ? bv.y : 0.f, bf);
    stout(out, o + 2, mykeep ? bv.z : 0.f, bf);
    stout(out, o + 3, mykeep ? bv.w : 0.f, bf);
    stout(out, o + 4, mykeep ? sc   : 0.f, bf);
  }
}

extern "C" void kernel_launch(void* const* d_in, const int* in_sizes, int n_in,
                              void* d_out, int out_size, void* d_ws, size_t ws_size,
                              hipStream_t stream) {
  const void* locs0 = d_in[0];
  const void* locs1 = d_in[1];
  const void* locs2 = d_in[2];
  const void* gt    = d_in[3];

  int ic[3], ir[3], it[3];
  if (n_in >= 13 && in_sizes[5] == 16 * 4096 * 20) {
    ic[0]=4; ic[1]=5; ic[2]=6;  ir[0]=7; ir[1]=8; ir[2]=9;  it[0]=10; it[1]=11; it[2]=12;
  } else {
    ic[0]=4; ic[1]=7; ic[2]=10; ir[0]=5; ir[1]=8; ir[2]=11; it[0]=6;  it[1]=9;  it[2]=12;
  }
  const void* cls0 = d_in[ic[0]]; const void* cls1 = d_in[ic[1]]; const void* cls2 = d_in[ic[2]];
  const void* reg0 = d_in[ir[0]]; const void* reg1 = d_in[ir[1]]; const void* reg2 = d_in[ir[2]];
  const void* ctr0 = d_in[it[0]]; const void* ctr1 = d_in[it[1]]; const void* ctr2 = d_in[it[2]];

  float* ws     = (float*)d_ws;
  float* scores = ws + WS_SCORES;
  float* boxesw = ws + WS_BOXESW;
  float* cidw   = ws + WS_CIDW;

  k_main<<<dim3(NT / 256, NB), 256, 0, stream>>>(locs0, locs1, locs2, gt,
                                                 cls0, cls1, cls2,
                                                 reg0, reg1, reg2,
                                                 ctr0, ctr1, ctr2,
                                                 d_out, scores, boxesw, cidw);
  k_post<<<NB, 1024, 0, stream>>>(scores, boxesw, cidw, d_out, locs0);
}

// Round 9
// 194.827 us; speedup vs baseline: 1.7152x; 1.7152x over previous
//
#include <hip/hip_runtime.h>
#include <hip/hip_bf16.h>
#include <math.h>
#include <stdint.h>

// Disable FP contraction: tie-breaking (quality = 1e8 - area, ulp=8 at 1e8)
// and decode must bit-match the mul-then-round numpy reference.
#pragma clang fp contract(off)

#define NB   16
#define NC   20
#define NM   64
#define NT   21504
#define OFF1 16384
#define OFF2 20480
#define TOPK 1000
#define DELTA_OFF 80000L
#define CTR_OFF   1456256L

// workspace layout (float units)
#define WS_SCORES   0L
#define WS_BOXESW   344064L
#define WS_CIDW     1720320L

// ---------- dtype helpers (bf: 0 = float32, 1 = bf16) ----------
__device__ __forceinline__ int detect_bf(const void* locs0) {
  unsigned w = *(const unsigned*)locs0;      // f32 4.0 = 0x40800000 (low16==0)
  return ((w & 0xFFFFu) == 0u) ? 0 : 1;
}
__device__ __forceinline__ float ldin(const void* p, long i, int bf) {
  if (bf) return __uint_as_float(((unsigned)((const unsigned short*)p)[i]) << 16);
  return ((const float*)p)[i];
}
__device__ __forceinline__ unsigned short f2bf(float v) {
  unsigned w = __float_as_uint(v);
  return (unsigned short)((w + 0x7FFFu + ((w >> 16) & 1u)) >> 16);  // RNE
}
__device__ __forceinline__ void stout(void* p, long i, float v, int bf) {
  if (bf) ((unsigned short*)p)[i] = f2bf(v);
  else    ((float*)p)[i] = v;
}

// ---------- K1: fused targets + scores/decode (proven) ----------
__global__ __launch_bounds__(256)
void k_main(const void* locs0, const void* locs1, const void* locs2,
            const void* gt,
            const void* cls0, const void* cls1, const void* cls2,
            const void* reg0, const void* reg1, const void* reg2,
            const void* ctr0, const void* ctr1, const void* ctr2,
            void* out, float* scores, float* boxesw, float* cidw) {
  __shared__ float sgt[NM * 5];
  const int bf  = detect_bf(locs0);
  const int b   = blockIdx.y;
  const int blk = blockIdx.x;
  const int tid = threadIdx.x;
  const int n   = blk * 256 + tid;

  const void *L, *CL, *RG, *CT; int NL, base; float stride, lower, upper;
  if (blk < 64)      { L=locs0; CL=cls0; RG=reg0; CT=ctr0; NL=16384; base=0;    stride=8.f;  lower=0.f;   upper=64.f; }
  else if (blk < 80) { L=locs1; CL=cls1; RG=reg1; CT=ctr1; NL=4096;  base=OFF1; stride=16.f; lower=64.f;  upper=128.f; }
  else               { L=locs2; CL=cls2; RG=reg2; CT=ctr2; NL=1024;  base=OFF2; stride=32.f; lower=128.f; upper=INFINITY; }
  const int nl = n - base;

  for (int i = tid; i < NM * 5; i += 256) sgt[i] = ldin(gt, (long)b * NM * 5 + i, bf);
  __syncthreads();

  float cx = ldin(L, (long)nl * 2 + 0, bf);
  float cy = ldin(L, (long)nl * 2 + 1, bf);

  // ---- GT matching / targets ----
  float best = -1.0f; int bi = 0;              // argmax-first (strict >)
  for (int m = 0; m < NM; ++m) {
    float g0 = sgt[m*5+0], g1 = sgt[m*5+1], g2 = sgt[m*5+2], g3 = sgt[m*5+3];
    float l = cx - g0, t = cy - g1, r = g2 - cx, d = g3 - cy;
    float mn = fminf(fminf(l, t), fminf(r, d));
    float mx = fmaxf(fmaxf(l, t), fmaxf(r, d));
    bool  ok = (mn > 0.f) && (mx > lower) && (mx < upper);
    float area = (g2 - g0) * (g3 - g1);
    float q = ok ? (100000000.0f - area) : 0.f;
    if (q > best) { best = q; bi = m; }
  }
  float d0, d1, d2, d3, ctrv;
  if (best < 1e-5f) {
    d0 = d1 = d2 = d3 = -1.f; ctrv = -1.f;
  } else {
    float m0 = sgt[bi*5+0], m1 = sgt[bi*5+1], m2 = sgt[bi*5+2], m3 = sgt[bi*5+3];
    d0 = (cx - m0) / stride; d1 = (cy - m1) / stride;
    d2 = (m2 - cx) / stride; d3 = (m3 - cy) / stride;
    float mnlr = fminf(d0, d2), mntb = fminf(d1, d3);
    float mxlr = fmaxf(d0, d2), mxtb = fmaxf(d1, d3);
    ctrv = sqrtf((mnlr * mntb) / (mxlr * mxtb));
  }
  long dbase = DELTA_OFF + ((long)b * NT + n) * 4;
  if (!bf) {
    *(float4*)((float*)out + dbase) = make_float4(d0, d1, d2, d3);
  } else {
    ushort4 v; v.x = f2bf(d0); v.y = f2bf(d1); v.z = f2bf(d2); v.w = f2bf(d3);
    *(ushort4*)((unsigned short*)out + dbase) = v;
  }
  stout(out, CTR_OFF + (long)b * NT + n, ctrv, bf);

  // ---- scores: argmax over sigmoid == argmax over logits (monotone) ----
  float ct  = ldin(CT, (long)b * NL + nl, bf);
  float sct = 1.0f / (1.0f + expf(-ct));

  float cl[NC];
  long cb = ((long)b * NL + nl) * NC;
  if (!bf) {
    const float4* p = (const float4*)((const float*)CL + cb);   // cb*4 % 16 == 0
#pragma unroll
    for (int i = 0; i < 5; ++i) {
      float4 q = p[i];
      cl[4*i+0] = q.x; cl[4*i+1] = q.y; cl[4*i+2] = q.z; cl[4*i+3] = q.w;
    }
  } else {
    const uint2* p = (const uint2*)((const unsigned short*)CL + cb);  // cb*2 % 8 == 0
#pragma unroll
    for (int i = 0; i < 5; ++i) {
      uint2 q = p[i];
      cl[4*i+0] = __uint_as_float((q.x & 0xFFFFu) << 16);
      cl[4*i+1] = __uint_as_float(q.x & 0xFFFF0000u);
      cl[4*i+2] = __uint_as_float((q.y & 0xFFFFu) << 16);
      cl[4*i+3] = __uint_as_float(q.y & 0xFFFF0000u);
    }
  }
  float vmax = cl[0], v2 = -INFINITY; int ci = 0;
#pragma unroll
  for (int c = 1; c < NC; ++c) {
    if (cl[c] > vmax) { v2 = vmax; vmax = cl[c]; ci = c; }
    else if (cl[c] > v2) v2 = cl[c];
  }
  float smax;
  if (vmax - v2 < 1e-3f) {
    // sigmoid-plateau risk: replicate the reference loop exactly (strict >, first idx)
    smax = -1.0f; ci = 0;
    for (int c = 0; c < NC; ++c) {
      float sv = 1.0f / (1.0f + expf(-cl[c]));
      float s  = sqrtf(sv * sct);
      if (s > smax) { smax = s; ci = c; }
    }
  } else {
    float sv = 1.0f / (1.0f + expf(-vmax));
    smax = sqrtf(sv * sct);      // == ref's max: RN is monotone under *sct and sqrt
  }

  // ---- decode ----
  float r0, r1, r2, r3;
  long rbase = ((long)b * NL + nl) * 4;
  if (!bf) {
    float4 rv = *(const float4*)((const float*)RG + rbase);
    r0 = rv.x; r1 = rv.y; r2 = rv.z; r3 = rv.w;
  } else {
    uint2 rw = *(const uint2*)((const unsigned short*)RG + rbase);
    r0 = __uint_as_float((rw.x & 0xFFFFu) << 16); r1 = __uint_as_float(rw.x & 0xFFFF0000u);
    r2 = __uint_as_float((rw.y & 0xFFFFu) << 16); r3 = __uint_as_float(rw.y & 0xFFFF0000u);
  }
  r0 = fmaxf(r0, 0.f); r1 = fmaxf(r1, 0.f); r2 = fmaxf(r2, 0.f); r3 = fmaxf(r3, 0.f);
  long o = (long)b * NT + n;
  scores[o] = smax;
  *(float4*)(boxesw + o * 4) =
      make_float4(cx - r0 * stride, cy - r1 * stride, cx + r2 * stride, cy + r3 * stride);
  cidw[o] = (float)ci;
}

// ---------- wave64 inclusive scan ----------
__device__ __forceinline__ unsigned wscan(unsigned v, int lane) {
  for (int off = 1; off < 64; off <<= 1) {
    unsigned u = __shfl_up(v, off);
    if (lane >= off) v += u;
  }
  return v;
}

// ---------- K2: top-1000 select + sort + 1-barrier-per-pick block NMS ----------
__global__ __launch_bounds__(1024)
void k_post(const float* scores, const float* boxesw, const float* cidw,
            void* out, const void* locs0) {
  const int bf   = detect_bf(locs0);
  const int b    = blockIdx.x;
  const int tid  = threadIdx.x;
  const int wid  = tid >> 6;
  const int lane = tid & 63;
  const float* sb = scores + (long)b * NT;

  __shared__ unsigned hist[8192];                       // 32 KB; aliased below
  unsigned long long* selKeys = (unsigned long long*)hist;  // [1024], alias (sort)
  float*              sb5     = (float*)hist;               // [1024*5], alias (NMS)
  __shared__ unsigned wsum[16];
  __shared__ unsigned sTop, sBefore, sBinCnt, sSub, selCnt;
  __shared__ float redf[16];
  __shared__ float sMaxC;
  __shared__ unsigned long long smaskInit[16];
  __shared__ unsigned long long smaskBuf[2][16];        // double-buffer: no 2nd barrier

  // ============ Phase A: exact top-1000 (histogram select + hybrid bitonic) ====
  unsigned inv[21];
#pragma unroll
  for (int k = 0; k < 21; ++k)
    inv[k] = ~__float_as_uint(sb[tid + k * 1024]);

  // level 1: histogram of inv>>17 (top 2 bits always 11 -> 8192 bins)
  for (int i = tid; i < 8192; i += 1024) hist[i] = 0u;
  __syncthreads();
#pragma unroll
  for (int k = 0; k < 21; ++k)
    atomicAdd(&hist[(inv[k] >> 17) - 0x6000u], 1u);
  __syncthreads();
  {
    unsigned hloc[8], s0 = 0;
#pragma unroll
    for (int j = 0; j < 8; ++j) { hloc[j] = hist[8 * tid + j]; s0 += hloc[j]; }
    unsigned sc = wscan(s0, lane);
    if (lane == 63) wsum[wid] = sc;
    __syncthreads();
    unsigned basev = 0;
    for (int w = 0; w < wid; ++w) basev += wsum[w];
    unsigned cumBefore = basev + sc - s0;
    if (cumBefore < TOPK && cumBefore + s0 >= TOPK) {
      unsigned c = cumBefore;
#pragma unroll
      for (int j = 0; j < 8; ++j) {
        if (c + hloc[j] >= TOPK) {
          sTop = (8 * tid + j) + 0x6000u; sBefore = c; sBinCnt = hloc[j]; break;
        }
        c += hloc[j];
      }
    }
  }
  __syncthreads();
  const unsigned topBits = sTop;
  const unsigned r = TOPK - sBefore;

  unsigned long long cutEnd;
  if (sBefore + sBinCnt <= 1024u) {
    // whole boundary bin fits the 1024 gather budget: skip level 2 (uniform branch)
    cutEnd = ((unsigned long long)(topBits + 1u)) << 17;
  } else {
    // level 2: histogram of bits 16..4 within boundary bin
    for (int i = tid; i < 8192; i += 1024) hist[i] = 0u;
    __syncthreads();
#pragma unroll
    for (int k = 0; k < 21; ++k)
      if ((inv[k] >> 17) == topBits) atomicAdd(&hist[(inv[k] >> 4) & 0x1FFFu], 1u);
    __syncthreads();
    {
      unsigned hloc[8], s0 = 0;
#pragma unroll
      for (int j = 0; j < 8; ++j) { hloc[j] = hist[8 * tid + j]; s0 += hloc[j]; }
      unsigned sc = wscan(s0, lane);
      if (lane == 63) wsum[wid] = sc;
      __syncthreads();
      unsigned basev = 0;
      for (int w = 0; w < wid; ++w) basev += wsum[w];
      unsigned cumBefore = basev + sc - s0;
      if (cumBefore < r && cumBefore + s0 >= r) {
        unsigned c = cumBefore;
#pragma unroll
        for (int j = 0; j < 8; ++j) {
          if (c + hloc[j] >= r) { sSub = 8 * tid + j; break; }
          c += hloc[j];
        }
      }
    }
    __syncthreads();
    cutEnd = ((unsigned long long)topBits << 17) |
             ((unsigned long long)(sSub + 1u) << 4);
  }
  if (tid == 0) selCnt = 0u;
  __syncthreads();   // hist reads done; selKeys alias safe

#pragma unroll
  for (int k = 0; k < 21; ++k)
    if ((unsigned long long)inv[k] < cutEnd) {
      unsigned p = atomicAdd(&selCnt, 1u);
      if (p < 1024u) selKeys[p] = ((unsigned long long)inv[k] << 32) | (unsigned)(tid + k * 1024);
    }
  __syncthreads();
  unsigned total = selCnt < 1024u ? selCnt : 1024u;
  unsigned long long key =
      ((unsigned)tid < total) ? selKeys[tid] : 0xFFFFFFFFFFFFFFFFull;
  __syncthreads();

  // hybrid bitonic sort ascending: (inv asc, idx asc) == (score desc, idx asc)
  for (unsigned k = 2; k <= 1024; k <<= 1) {
    for (unsigned j = k >> 1; j > 0; j >>= 1) {
      unsigned long long other;
      if (j >= 64) {
        selKeys[tid] = key; __syncthreads();
        other = selKeys[tid ^ j]; __syncthreads();
      } else {
        other = __shfl(key, (int)(lane ^ j));
      }
      bool up = ((tid & k) == 0);
      bool takeMin = (((tid & j) == 0) == up);
      key = takeMin ? (key < other ? key : other) : (key > other ? key : other);
    }
  }

  // ---- gather box/score/cls (registers) ----
  float sc = __uint_as_float(~(unsigned)(key >> 32));
  float4 bv = make_float4(0.f, 0.f, 0.f, 0.f);
  float cid = 0.f;
  if (tid < TOPK) {
    long o = (long)b * NT + (unsigned)key;
    bv = *(const float4*)(boxesw + o * 4);
    cid = cidw[o];
  } else sc = 0.f;

  // ---- max_coord = max(where(valid, bx, 0)) ----
  float loc = (tid < TOPK)
      ? ((sc > 0.3f) ? fmaxf(fmaxf(bv.x, bv.y), fmaxf(bv.z, bv.w)) : 0.0f)
      : -INFINITY;
  for (int o = 32; o > 0; o >>= 1) loc = fmaxf(loc, __shfl_down(loc, o));
  if (lane == 0) redf[wid] = loc;
  __syncthreads();
  if (tid == 0) {
    float m = redf[0];
    for (int w = 1; w < 16; ++w) m = fmaxf(m, redf[w]);
    sMaxC = m;
  }
  __syncthreads();

  // ---- shifted box + area: registers AND LDS (sb5: stride-5, conflict-free) ----
  float offm = sMaxC + 1.0f;
  float o4 = cid * offm;
  float s0 = bv.x + o4, s1 = bv.y + o4, s2 = bv.z + o4, s3 = bv.w + o4;
  float myArea = (s2 - s0) * (s3 - s1);
  sb5[tid*5+0] = s0; sb5[tid*5+1] = s1; sb5[tid*5+2] = s2; sb5[tid*5+3] = s3;
  sb5[tid*5+4] = myArea;
  bool valid = (tid < TOPK) && (sc > 0.3f);
  unsigned long long vb = __ballot(valid);
  if (lane == 0) smaskInit[wid] = vb;
  __syncthreads();   // sb5 + smaskInit ready

  // ============ Phase B: block-parallel NMS, ONE barrier per pick ============
  // Every wave redundantly holds all 16 act words (word w in lane w) and
  // recomputes the pick after each barrier — identical across waves.
  unsigned long long actW = (lane < 16) ? smaskInit[lane] : 0ull;
  int pick;
  {
    int cand = actW ? (lane * 64 + __ffsll(actW) - 1) : 0x7FFFFFFF;
    for (int o = 8; o > 0; o >>= 1) cand = min(cand, __shfl_down(cand, o));
    pick = __shfl(cand, 0);
  }
  bool mykeep = false;
  int kept = 0;
  while (pick < 0x7FFFFFFF && kept < 100) {
    if (tid == pick) mykeep = true;
    // IoU of my row (registers) vs picked box (same-address LDS broadcast)
    float p0 = sb5[pick*5+0], p1 = sb5[pick*5+1];
    float p2 = sb5[pick*5+2], p3 = sb5[pick*5+3], pa = sb5[pick*5+4];
    float xx1 = fmaxf(p0, s0), yy1 = fmaxf(p1, s1);
    float xx2 = fminf(p2, s2), yy2 = fminf(p3, s3);
    float inter = fmaxf(xx2 - xx1, 0.f) * fmaxf(yy2 - yy1, 0.f);
    float iou = inter / (pa + myArea - inter);        // exact div: ref rounding
    bool sup = (tid < TOPK) && !(iou <= 0.5f);        // NaN suppresses (self too)
    unsigned long long sm = __ballot(sup);
    if (lane == 0) smaskBuf[kept & 1][wid] = sm;
    __syncthreads();                                  // the ONLY barrier per pick
    unsigned long long clr = (lane < 16) ? smaskBuf[kept & 1][lane] : 0ull;
    actW &= ~clr;
    ++kept;
    int cand = actW ? (lane * 64 + __ffsll(actW) - 1) : 0x7FFFFFFF;
    for (int o = 8; o > 0; o >>= 1) cand = min(cand, __shfl_down(cand, o));
    pick = __shfl(cand, 0);
  }

  // ---- det write from registers (no LDS dependence) ----
  if (tid < TOPK) {
    long o = ((long)b * TOPK + tid) * 5;
    stout(out, o + 0, mykeep ? bv.x : 0.f, bf);
    stout(out, o + 1, mykeep ? bv.y : 0.f, bf);
    stout(out, o + 2, mykeep ? bv.z : 0.f, bf);
    stout(out, o + 3, mykeep ? bv.w : 0.f, bf);
    stout(out, o + 4, mykeep ? sc   : 0.f, bf);
  }
}

extern "C" void kernel_launch(void* const* d_in, const int* in_sizes, int n_in,
                              void* d_out, int out_size, void* d_ws, size_t ws_size,
                              hipStream_t stream) {
  const void* locs0 = d_in[0];
  const void* locs1 = d_in[1];
  const void* locs2 = d_in[2];
  const void* gt    = d_in[3];

  int ic[3], ir[3], it[3];
  if (n_in >= 13 && in_sizes[5] == 16 * 4096 * 20) {
    ic[0]=4; ic[1]=5; ic[2]=6;  ir[0]=7; ir[1]=8; ir[2]=9;  it[0]=10; it[1]=11; it[2]=12;
  } else {
    ic[0]=4; ic[1]=7; ic[2]=10; ir[0]=5; ir[1]=8; ir[2]=11; it[0]=6;  it[1]=9;  it[2]=12;
  }
  const void* cls0 = d_in[ic[0]]; const void* cls1 = d_in[ic[1]]; const void* cls2 = d_in[ic[2]];
  const void* reg0 = d_in[ir[0]]; const void* reg1 = d_in[ir[1]]; const void* reg2 = d_in[ir[2]];
  const void* ctr0 = d_in[it[0]]; const void* ctr1 = d_in[it[1]]; const void* ctr2 = d_in[it[2]];

  float* ws     = (float*)d_ws;
  float* scores = ws + WS_SCORES;
  float* boxesw = ws + WS_BOXESW;
  float* cidw   = ws + WS_CIDW;

  k_main<<<dim3(NT / 256, NB), 256, 0, stream>>>(locs0, locs1, locs2, gt,
                                                 cls0, cls1, cls2,
                                                 reg0, reg1, reg2,
                                                 ctr0, ctr1, ctr2,
                                                 d_out, scores, boxesw, cidw);
  k_post<<<NB, 1024, 0, stream>>>(scores, boxesw, cidw, d_out, locs0);
}